// Round 15
// baseline (115.093 us; speedup 1.0000x reference)
//
#include <hip/hip_runtime.h>
#include <hip/hip_bf16.h>

#define NB 2048
#define SA 121
#define EMB_TOTAL (NB * 64 * SA)   // 15,859,712 floats

typedef short bf16x8 __attribute__((ext_vector_type(8)));
typedef float f32x4  __attribute__((ext_vector_type(4)));
typedef unsigned int u32x2 __attribute__((ext_vector_type(2)));

__device__ __forceinline__ short f2bf(float f) {   // native RNE cvt
    union { __hip_bfloat16 h; short s; } u;
    u.h = __float2bfloat16(f);
    return u.s;
}
__device__ __forceinline__ unsigned pack2(float a, float b) {   // low short = a
    union { __hip_bfloat16 h[2]; unsigned u; } p;
    p.h[0] = __float2bfloat16(a);
    p.h[1] = __float2bfloat16(b);
    return p.u;
}

#define MFMA(a, b, c) __builtin_amdgcn_mfma_f32_16x16x32_bf16((a), (b), (c), 0, 0, 0)

// Convert f32 weights -> zero-padded bf16 copies in workspace.
// ws layout (shorts): WQ[128*128] @0, WK @16384, WV @32768, WC[64*128] @49152
__global__ void convert_weights(const float* __restrict__ Wq, const float* __restrict__ Wk,
                                const float* __restrict__ Wv, const float* __restrict__ Wc,
                                short* __restrict__ ws) {
    int i = blockIdx.x * 256 + threadIdx.x;   // 0 .. 57343
    if (i < 49152) {
        int m = i / 16384;
        const float* W = (m == 0) ? Wq : ((m == 1) ? Wk : Wv);
        int j = i & 16383;
        int r = j >> 7, c = j & 127;
        float v = (r < SA && c < SA) ? W[r * SA + c] : 0.f;
        ws[i] = f2bf(v);
    } else {
        int j = i - 49152;                    // Wc is exactly [64][128]
        ws[i] = f2bf(Wc[j]);
    }
}

__launch_bounds__(256, 2)
__global__ void fused_kernel(const float* __restrict__ lidar, const float* __restrict__ hsi,
                             const float* __restrict__ bq, const float* __restrict__ bk,
                             const float* __restrict__ bv,
                             const float* __restrict__ Wr1, const float* __restrict__ br1,
                             const float* __restrict__ Wr2, const float* __restrict__ br2,
                             const float* __restrict__ bc,
                             const short* __restrict__ wsb, float* __restrict__ out) {
    // LDS ~81.4 KB -> 2 blocks/CU
    __shared__ __align__(16) short sA[64 * 136];   // lidar bf16 [ch][s], stride 136
    __shared__ __align__(16) short sB[64 * 136];   // hsi (written mid-dir0 from regs)
    __shared__ __align__(16) short sC[64 * 136];   // q
    __shared__ __align__(16) short sD[128 * 72];   // k as [64][136], then G^T as [128][72]
    __shared__ __align__(16) short sE[64 * 72];    // P^T [g][h], then M [o][g]
    __shared__ float sR[260];                      // pooled[128], hidden[128], logits[4]

    const int tid  = threadIdx.x;
    const int b    = blockIdx.x;
    const int lane = tid & 63;
    const int wid  = tid >> 6;
    const int l16  = lane & 15;
    const int g16  = lane >> 4;

    const short* WQ = wsb;
    const short* WK = wsb + 16384;
    const short* WV = wsb + 32768;
    const short* WC = wsb + 49152;

    // ---- persistent weight fragments: Q/K only (V and C loaded on demand in phase C) -
    bf16x8 wqf[2][4], wkf[2][4];
    #pragma unroll
    for (int nn = 0; nn < 2; ++nn) {
        const int rw = ((wid * 2 + nn) * 16 + l16) * 128 + g16 * 8;
        #pragma unroll
        for (int k0 = 0; k0 < 4; ++k0) {
            wqf[nn][k0] = *(const bf16x8*)&WQ[rw + k0 * 32];
            wkf[nn][k0] = *(const bf16x8*)&WK[rw + k0 * 32];
        }
    }
    float bqv[2], bkv[2], bvv2[2];
    #pragma unroll
    for (int nn = 0; nn < 2; ++nn) {
        int sc_ = (wid * 2 + nn) * 16 + l16;
        bool ok = sc_ < SA;
        bqv[nn]  = ok ? bq[sc_] : 0.f;
        bkv[nn]  = ok ? bk[sc_] : 0.f;
        bvv2[nn] = ok ? bv[sc_] : 0.f;
    }

    const int row = wid * 16 + l16;

    // ---- prefetch hsi into registers (latency hides under bar0 + phases A,B) ----
    float vb[32];
    {
        const float* gB = hsi + (size_t)b * 7744 + row * 121;
        #pragma unroll
        for (int k0 = 0; k0 < 4; ++k0) {
            const int c0 = k0 * 32 + g16 * 8;
            if (c0 == 120) {
                vb[k0 * 8] = gB[120];
                #pragma unroll
                for (int j = 1; j < 8; ++j) vb[k0 * 8 + j] = 0.f;
            } else {
                #pragma unroll
                for (int j = 0; j < 8; ++j) vb[k0 * 8 + j] = gB[c0 + j];
            }
        }
    }

    // ---- stage lidar -> sA (bf16, fragment layout) + router row-sum ----
    {
        const float* gA = lidar + (size_t)b * 7744 + row * 121;
        float rsA = 0.f;
        #pragma unroll
        for (int k0 = 0; k0 < 4; ++k0) {
            const int c0 = k0 * 32 + g16 * 8;
            bf16x8 a;
            if (c0 == 120) {
                float xa = gA[120];
                rsA += xa;
                a[0] = f2bf(xa);
                #pragma unroll
                for (int j = 1; j < 8; ++j) a[j] = 0;
            } else {
                #pragma unroll
                for (int j = 0; j < 8; ++j) {
                    float xa = gA[c0 + j];
                    rsA += xa;
                    a[j] = f2bf(xa);
                }
            }
            *(bf16x8*)&sA[row * 136 + c0] = a;
        }
        rsA += __shfl_xor(rsA, 16, 64); rsA += __shfl_xor(rsA, 32, 64);
        if (g16 == 0) sR[row] = rsA * (1.f / 121.f);
    }
    __syncthreads();   // bar0 (sA ready; sB NOT yet — not needed until dir0 phase C)

    f32x4 eacc[8];
    #pragma unroll
    for (int n = 0; n < 8; ++n) eacc[n] = (f32x4){0.f, 0.f, 0.f, 0.f};

    #pragma unroll 1
    for (int dir = 0; dir < 2; ++dir) {
        const short* Xqk = dir ? sB : sA;
        const short* Xv  = dir ? sA : sB;
        const int cb = dir ? 0 : 1;   // Wc col-half: dir0 -> cols 64:, dir1 -> cols :64

        f32x4 qs[4][2];   // q (+bias, f32) persisted for the phase-C gate

        // ========== phase A: q -> sC (+qs regs), k -> sD ==============================
        #pragma unroll
        for (int m = 0; m < 4; ++m) {
            bf16x8 afr[4];
            #pragma unroll
            for (int k0 = 0; k0 < 4; ++k0)
                afr[k0] = *(const bf16x8*)&Xqk[(m * 16 + l16) * 136 + k0 * 32 + g16 * 8];
            f32x4 qa[2], ka[2];
            qa[0] = (f32x4){0,0,0,0}; qa[1] = (f32x4){0,0,0,0};
            ka[0] = (f32x4){0,0,0,0}; ka[1] = (f32x4){0,0,0,0};
            #pragma unroll
            for (int k0 = 0; k0 < 4; ++k0)
                #pragma unroll
                for (int nn = 0; nn < 2; ++nn) {
                    qa[nn] = MFMA(afr[k0], wqf[nn][k0], qa[nn]);
                    ka[nn] = MFMA(afr[k0], wkf[nn][k0], ka[nn]);
                }
            #pragma unroll
            for (int nn = 0; nn < 2; ++nn) {
                int sc_ = (wid * 2 + nn) * 16 + l16;
                #pragma unroll
                for (int r = 0; r < 4; ++r) {
                    int row2 = m * 16 + g16 * 4 + r;
                    float qv = qa[nn][r] + bqv[nn];
                    qs[m][nn][r] = qv;
                    sC[row2 * 136 + sc_] = f2bf(qv);
                    sD[row2 * 136 + sc_] = f2bf(ka[nn][r] + bkv[nn]);
                }
            }
        }
        __syncthreads();   // bar1

        // ========== phase B: scores = q @ k^T, softmax, P^T -> sE (packed) ============
        {
            f32x4 sc4[4];
            #pragma unroll
            for (int n = 0; n < 4; ++n) sc4[n] = (f32x4){0,0,0,0};
            #pragma unroll
            for (int k0 = 0; k0 < 4; ++k0) {
                bf16x8 afr = *(const bf16x8*)&sC[(wid * 16 + l16) * 136 + k0 * 32 + g16 * 8];
                #pragma unroll
                for (int n = 0; n < 4; ++n) {
                    bf16x8 bfr = *(const bf16x8*)&sD[(n * 16 + l16) * 136 + k0 * 32 + g16 * 8];
                    sc4[n] = MFMA(afr, bfr, sc4[n]);
                }
            }
            float p[4][4];
            #pragma unroll
            for (int r = 0; r < 4; ++r) {
                float mx = fmaxf(fmaxf(sc4[0][r], sc4[1][r]), fmaxf(sc4[2][r], sc4[3][r]));
                #pragma unroll
                for (int off = 1; off < 16; off <<= 1) mx = fmaxf(mx, __shfl_xor(mx, off, 64));
                float e0 = exp2f((sc4[0][r] - mx) * 1.44269504f);
                float e1 = exp2f((sc4[1][r] - mx) * 1.44269504f);
                float e2 = exp2f((sc4[2][r] - mx) * 1.44269504f);
                float e3 = exp2f((sc4[3][r] - mx) * 1.44269504f);
                float sum = e0 + e1 + e2 + e3;
                #pragma unroll
                for (int off = 1; off < 16; off <<= 1) sum += __shfl_xor(sum, off, 64);
                float inv = 1.f / sum;
                p[0][r] = e0 * inv; p[1][r] = e1 * inv; p[2][r] = e2 * inv; p[3][r] = e3 * inv;
            }
            #pragma unroll
            for (int n = 0; n < 4; ++n) {   // P^T[g][h]: 4 r-consecutive h -> one b64
                u32x2 pk;
                pk.x = pack2(p[n][0], p[n][1]);
                pk.y = pack2(p[n][2], p[n][3]);
                *(u32x2*)&sE[(n * 16 + l16) * 72 + wid * 16 + g16 * 4] = pk;
            }
        }

        // ---- deferred sB write (dir0 only): hsi regs -> LDS + router row-sum ----
        if (dir == 0) {
            float rsB = 0.f;
            #pragma unroll
            for (int k0 = 0; k0 < 4; ++k0) {
                const int c0 = k0 * 32 + g16 * 8;
                bf16x8 h;
                #pragma unroll
                for (int j = 0; j < 8; ++j) {
                    rsB += vb[k0 * 8 + j];
                    h[j] = f2bf(vb[k0 * 8 + j]);
                }
                *(bf16x8*)&sB[row * 136 + c0] = h;
            }
            rsB += __shfl_xor(rsB, 16, 64); rsB += __shfl_xor(rsB, 32, 64);
            if (g16 == 0) sR[64 + row] = rsB * (1.f / 121.f);
        }
        __syncthreads();   // bar2 (P^T ready AND sB ready)

        // ====== phase C: M-MFMAs FIRST (WV/WC on demand), then v+gate(qs), ONE bar ====
        {
            // on-demand weight fragments (L2-hot, shared by all blocks)
            bf16x8 wvl[2][4];
            #pragma unroll
            for (int nn = 0; nn < 2; ++nn) {
                const int rw = ((wid * 2 + nn) * 16 + l16) * 128 + g16 * 8;
                #pragma unroll
                for (int k0 = 0; k0 < 4; ++k0)
                    wvl[nn][k0] = *(const bf16x8*)&WV[rw + k0 * 32];
            }
            const int rwc = (wid * 16 + l16) * 128 + cb * 64 + g16 * 8;
            bf16x8 wc0 = *(const bf16x8*)&WC[rwc];
            bf16x8 wc1 = *(const bf16x8*)&WC[rwc + 32];
            // M = Wc[:, cb*64 .. +64) @ P  -> registers
            f32x4 macc[4];
            #pragma unroll
            for (int n = 0; n < 4; ++n) macc[n] = (f32x4){0,0,0,0};
            #pragma unroll
            for (int n = 0; n < 4; ++n) {
                bf16x8 b0 = *(const bf16x8*)&sE[(n * 16 + l16) * 72 + g16 * 8];
                bf16x8 b1 = *(const bf16x8*)&sE[(n * 16 + l16) * 72 + 32 + g16 * 8];
                macc[n] = MFMA(wc0, b0, macc[n]);
                macc[n] = MFMA(wc1, b1, macc[n]);
            }
            // v-proj + gate (q from qs regs, f32) -> G^T in sD (packed b64)
            #pragma unroll
            for (int m = 0; m < 4; ++m) {
                bf16x8 afr[4];
                #pragma unroll
                for (int k0 = 0; k0 < 4; ++k0)
                    afr[k0] = *(const bf16x8*)&Xv[(m * 16 + l16) * 136 + k0 * 32 + g16 * 8];
                f32x4 va[2];
                va[0] = (f32x4){0,0,0,0}; va[1] = (f32x4){0,0,0,0};
                #pragma unroll
                for (int k0 = 0; k0 < 4; ++k0)
                    #pragma unroll
                    for (int nn = 0; nn < 2; ++nn)
                        va[nn] = MFMA(afr[k0], wvl[nn][k0], va[nn]);
                #pragma unroll
                for (int nn = 0; nn < 2; ++nn) {
                    int sc_ = (wid * 2 + nn) * 16 + l16;
                    float g0 = (va[nn][0] + bvv2[nn]) * qs[m][nn][0];
                    float g1 = (va[nn][1] + bvv2[nn]) * qs[m][nn][1];
                    float g2 = (va[nn][2] + bvv2[nn]) * qs[m][nn][2];
                    float g3 = (va[nn][3] + bvv2[nn]) * qs[m][nn][3];
                    u32x2 pk;
                    pk.x = pack2(g0, g1);
                    pk.y = pack2(g2, g3);
                    *(u32x2*)&sD[sc_ * 72 + m * 16 + g16 * 4] = pk;   // G^T [s][c]
                }
            }
            __syncthreads();   // bar3: all P^T reads done (M in regs) + all G^T writes done
            // M -> sE (own-wave rows; phase D needs no barrier, only lgkmcnt)
            #pragma unroll
            for (int n = 0; n < 4; ++n)
                #pragma unroll
                for (int r = 0; r < 4; ++r) {
                    int o = wid * 16 + g16 * 4 + r;
                    sE[o * 72 + n * 16 + l16] = f2bf(macc[n][r]);   // M [o][g]
                }
        }

        // ========== phase D: emb += M @ G (M same-wave rows; G^T bar3-protected) ======
        #pragma unroll
        for (int k0 = 0; k0 < 2; ++k0) {
            bf16x8 afr = *(const bf16x8*)&sE[(wid * 16 + l16) * 72 + k0 * 32 + g16 * 8];
            #pragma unroll
            for (int n = 0; n < 8; ++n) {
                bf16x8 bfr = *(const bf16x8*)&sD[(n * 16 + l16) * 72 + k0 * 32 + g16 * 8];
                eacc[n] = MFMA(afr, bfr, eacc[n]);
            }
        }
        if (dir == 0) __syncthreads();   // bar4 (only needed before dir1 reuses sC/sD/sE)
    }

    // ---- epilogue: emb + bc -> global ----
    float* eo = out + (size_t)b * 7744;
    {
        float bcv[4];
        #pragma unroll
        for (int r = 0; r < 4; ++r) bcv[r] = bc[wid * 16 + g16 * 4 + r];
        #pragma unroll
        for (int n = 0; n < 8; ++n) {
            int s = n * 16 + l16;
            if (s < SA) {
                #pragma unroll
                for (int r = 0; r < 4; ++r) {
                    int o = wid * 16 + g16 * 4 + r;
                    eo[o * 121 + s] = eacc[n][r] + bcv[r];
                }
            }
        }
    }

    // ---- router MLP (8-way unrolled: 8 loads in flight) ----
    if (tid < 128) {
        float a[8];
        #pragma unroll
        for (int j = 0; j < 8; ++j) a[j] = 0.f;
        for (int c = 0; c < 128; c += 8) {
            #pragma unroll
            for (int j = 0; j < 8; ++j)
                a[j] += sR[c + j] * Wr1[(c + j) * 128 + tid];
        }
        float s01 = a[0] + a[1], s23 = a[2] + a[3], s45 = a[4] + a[5], s67 = a[6] + a[7];
        sR[128 + tid] = fmaxf((s01 + s23) + (s45 + s67) + br1[tid], 0.f);
    }
    __syncthreads();
    if (tid < 4) {
        float a[8];
        #pragma unroll
        for (int j = 0; j < 8; ++j) a[j] = 0.f;
        for (int h = 0; h < 128; h += 8) {
            #pragma unroll
            for (int j = 0; j < 8; ++j)
                a[j] += sR[128 + h + j] * Wr2[(h + j) * 4 + tid];
        }
        float s01 = a[0] + a[1], s23 = a[2] + a[3], s45 = a[4] + a[5], s67 = a[6] + a[7];
        sR[256 + tid] = (s01 + s23) + (s45 + s67) + br2[tid];
    }
    __syncthreads();
    if (tid < 4) {
        float m = fmaxf(fmaxf(sR[256], sR[257]), fmaxf(sR[258], sR[259]));
        float e = __expf(sR[256 + tid] - m);
        float s = 0.f;
        for (int p = 0; p < 4; ++p) s += __expf(sR[256 + p] - m);
        out[EMB_TOTAL + b * 4 + tid] = e / s;
    }
}

extern "C" void kernel_launch(void* const* d_in, const int* in_sizes, int n_in,
                              void* d_out, int out_size, void* d_ws, size_t ws_size,
                              hipStream_t stream) {
    const float* lidar = (const float*)d_in[0];
    const float* hsi   = (const float*)d_in[1];
    const float* Wq  = (const float*)d_in[2];  const float* bq  = (const float*)d_in[3];
    const float* Wk  = (const float*)d_in[4];  const float* bk  = (const float*)d_in[5];
    const float* Wv  = (const float*)d_in[6];  const float* bv  = (const float*)d_in[7];
    const float* Wr1 = (const float*)d_in[8];  const float* br1 = (const float*)d_in[9];
    const float* Wr2 = (const float*)d_in[10]; const float* br2 = (const float*)d_in[11];
    const float* Wc  = (const float*)d_in[12]; const float* bc  = (const float*)d_in[13];
    short* wsb = (short*)d_ws;
    float* out = (float*)d_out;

    hipLaunchKernelGGL(convert_weights, dim3(224), dim3(256), 0, stream, Wq, Wk, Wv, Wc, wsb);
    hipLaunchKernelGGL(fused_kernel, dim3(NB), dim3(256), 0, stream,
                       lidar, hsi, bq, bk, bv, Wr1, br1, Wr2, br2, bc, wsb, out);
}

// Round 16
// 104.691 us; speedup vs baseline: 1.0994x; 1.0994x over previous
//
#include <hip/hip_runtime.h>
#include <hip/hip_bf16.h>

#define NB 2048
#define SA 121
#define EMB_TOTAL (NB * 64 * SA)   // 15,859,712 floats

typedef short bf16x8 __attribute__((ext_vector_type(8)));
typedef float f32x4  __attribute__((ext_vector_type(4)));
typedef unsigned int u32x2 __attribute__((ext_vector_type(2)));

__device__ __forceinline__ short f2bf(float f) {   // native RNE cvt
    union { __hip_bfloat16 h; short s; } u;
    u.h = __float2bfloat16(f);
    return u.s;
}
__device__ __forceinline__ float bf2f(short s) {
    union { unsigned u; float f; } v; v.u = ((unsigned)(unsigned short)s) << 16;
    return v.f;
}
__device__ __forceinline__ unsigned pack2(float a, float b) {   // low short = a
    union { __hip_bfloat16 h[2]; unsigned u; } p;
    p.h[0] = __float2bfloat16(a);
    p.h[1] = __float2bfloat16(b);
    return p.u;
}

#define MFMA(a, b, c) __builtin_amdgcn_mfma_f32_16x16x32_bf16((a), (b), (c), 0, 0, 0)

// Convert f32 weights -> zero-padded bf16 copies in workspace.
// ws layout (shorts): WQ[128*128] @0, WK @16384, WV @32768, WC[64*128] @49152
__global__ void convert_weights(const float* __restrict__ Wq, const float* __restrict__ Wk,
                                const float* __restrict__ Wv, const float* __restrict__ Wc,
                                short* __restrict__ ws) {
    int i = blockIdx.x * 256 + threadIdx.x;   // 0 .. 57343
    if (i < 49152) {
        int m = i / 16384;
        const float* W = (m == 0) ? Wq : ((m == 1) ? Wk : Wv);
        int j = i & 16383;
        int r = j >> 7, c = j & 127;
        float v = (r < SA && c < SA) ? W[r * SA + c] : 0.f;
        ws[i] = f2bf(v);
    } else {
        int j = i - 49152;                    // Wc is exactly [64][128]
        ws[i] = f2bf(Wc[j]);
    }
}

__launch_bounds__(256, 2)
__global__ void fused_kernel(const float* __restrict__ lidar, const float* __restrict__ hsi,
                             const float* __restrict__ bq, const float* __restrict__ bk,
                             const float* __restrict__ bv,
                             const float* __restrict__ Wr1, const float* __restrict__ br1,
                             const float* __restrict__ Wr2, const float* __restrict__ br2,
                             const float* __restrict__ bc,
                             const short* __restrict__ wsb, float* __restrict__ out) {
    // LDS ~81.4 KB -> 2 blocks/CU
    __shared__ __align__(16) short sA[64 * 136];   // lidar bf16 [ch][s], stride 136
    __shared__ __align__(16) short sB[64 * 136];   // hsi
    __shared__ __align__(16) short sC[64 * 136];   // q
    __shared__ __align__(16) short sD[128 * 72];   // k as [64][136], then G^T as [128][72]
    __shared__ __align__(16) short sE[64 * 72];    // P^T [g][h], then M [o][g]
    __shared__ float sR[260];                      // pooled[128], hidden[128], logits[4]

    const int tid  = threadIdx.x;
    const int b    = blockIdx.x;
    const int lane = tid & 63;
    const int wid  = tid >> 6;
    const int l16  = lane & 15;
    const int g16  = lane >> 4;

    const short* WQ = wsb;
    const short* WK = wsb + 16384;
    const short* WV = wsb + 32768;
    const short* WC = wsb + 49152;

    // ---- weight fragments: Q/K/V held in registers across BOTH directions ----
    // (WC loaded on demand in phase C — preloading it spilled 16 VGPRs, r13 lesson)
    bf16x8 wqf[2][4], wkf[2][4], wvf[2][4];
    #pragma unroll
    for (int nn = 0; nn < 2; ++nn) {
        const int rw = ((wid * 2 + nn) * 16 + l16) * 128 + g16 * 8;
        #pragma unroll
        for (int k0 = 0; k0 < 4; ++k0) {
            wqf[nn][k0] = *(const bf16x8*)&WQ[rw + k0 * 32];
            wkf[nn][k0] = *(const bf16x8*)&WK[rw + k0 * 32];
            wvf[nn][k0] = *(const bf16x8*)&WV[rw + k0 * 32];
        }
    }
    float bqv[2], bkv[2], bvv2[2];
    #pragma unroll
    for (int nn = 0; nn < 2; ++nn) {
        int sc_ = (wid * 2 + nn) * 16 + l16;
        bool ok = sc_ < SA;
        bqv[nn]  = ok ? bq[sc_] : 0.f;
        bkv[nn]  = ok ? bk[sc_] : 0.f;
        bvv2[nn] = ok ? bv[sc_] : 0.f;
    }

    // ---- stage lidar/hsi -> LDS bf16 (fragment layout) + router row-sums ----
    {
        const int row = wid * 16 + l16;
        const float* gA = lidar + (size_t)b * 7744 + row * 121;
        const float* gB = hsi   + (size_t)b * 7744 + row * 121;
        float rsA = 0.f, rsB = 0.f;
        #pragma unroll
        for (int k0 = 0; k0 < 4; ++k0) {
            const int c0 = k0 * 32 + g16 * 8;
            bf16x8 a, h;
            if (c0 == 120) {                       // cols 120..127 (121..127 K-pad = 0)
                float xa = gA[120], xb = gB[120];
                rsA += xa; rsB += xb;
                a[0] = f2bf(xa); h[0] = f2bf(xb);
                #pragma unroll
                for (int j = 1; j < 8; ++j) { a[j] = 0; h[j] = 0; }
            } else {
                #pragma unroll
                for (int j = 0; j < 8; ++j) {
                    float xa = gA[c0 + j], xb = gB[c0 + j];
                    rsA += xa; rsB += xb;
                    a[j] = f2bf(xa); h[j] = f2bf(xb);
                }
            }
            *(bf16x8*)&sA[row * 136 + c0] = a;
            *(bf16x8*)&sB[row * 136 + c0] = h;
        }
        rsA += __shfl_xor(rsA, 16, 64); rsA += __shfl_xor(rsA, 32, 64);
        rsB += __shfl_xor(rsB, 16, 64); rsB += __shfl_xor(rsB, 32, 64);
        if (g16 == 0) { sR[row] = rsA * (1.f / 121.f); sR[64 + row] = rsB * (1.f / 121.f); }
    }
    __syncthreads();   // bar0

    f32x4 eacc[8];
    #pragma unroll
    for (int n = 0; n < 8; ++n) eacc[n] = (f32x4){0.f, 0.f, 0.f, 0.f};

    #pragma unroll 1
    for (int dir = 0; dir < 2; ++dir) {
        const short* Xqk = dir ? sB : sA;
        const short* Xv  = dir ? sA : sB;
        const int cb = dir ? 0 : 1;   // Wc col-half: dir0 -> cols 64:, dir1 -> cols :64

        // ========== phase A: q -> sC, k -> sD (wave owns out-cols) ====================
        #pragma unroll
        for (int m = 0; m < 4; ++m) {
            bf16x8 afr[4];
            #pragma unroll
            for (int k0 = 0; k0 < 4; ++k0)
                afr[k0] = *(const bf16x8*)&Xqk[(m * 16 + l16) * 136 + k0 * 32 + g16 * 8];
            f32x4 qa[2], ka[2];
            qa[0] = (f32x4){0,0,0,0}; qa[1] = (f32x4){0,0,0,0};
            ka[0] = (f32x4){0,0,0,0}; ka[1] = (f32x4){0,0,0,0};
            __builtin_amdgcn_s_setprio(1);
            #pragma unroll
            for (int k0 = 0; k0 < 4; ++k0)
                #pragma unroll
                for (int nn = 0; nn < 2; ++nn) {
                    qa[nn] = MFMA(afr[k0], wqf[nn][k0], qa[nn]);
                    ka[nn] = MFMA(afr[k0], wkf[nn][k0], ka[nn]);
                }
            __builtin_amdgcn_s_setprio(0);
            #pragma unroll
            for (int nn = 0; nn < 2; ++nn) {
                int sc_ = (wid * 2 + nn) * 16 + l16;
                #pragma unroll
                for (int r = 0; r < 4; ++r) {
                    int row = m * 16 + g16 * 4 + r;
                    sC[row * 136 + sc_] = f2bf(qa[nn][r] + bqv[nn]);
                    sD[row * 136 + sc_] = f2bf(ka[nn][r] + bkv[nn]);
                }
            }
        }
        __syncthreads();   // bar1

        // ========== phase B: scores = q @ k^T, softmax, P^T -> sE (packed) ============
        {
            f32x4 sc4[4];
            #pragma unroll
            for (int n = 0; n < 4; ++n) sc4[n] = (f32x4){0,0,0,0};
            __builtin_amdgcn_s_setprio(1);
            #pragma unroll
            for (int k0 = 0; k0 < 4; ++k0) {
                bf16x8 afr = *(const bf16x8*)&sC[(wid * 16 + l16) * 136 + k0 * 32 + g16 * 8];
                #pragma unroll
                for (int n = 0; n < 4; ++n) {
                    bf16x8 bfr = *(const bf16x8*)&sD[(n * 16 + l16) * 136 + k0 * 32 + g16 * 8];
                    sc4[n] = MFMA(afr, bfr, sc4[n]);
                }
            }
            __builtin_amdgcn_s_setprio(0);
            float p[4][4];
            #pragma unroll
            for (int r = 0; r < 4; ++r) {
                float mx = fmaxf(fmaxf(sc4[0][r], sc4[1][r]), fmaxf(sc4[2][r], sc4[3][r]));
                #pragma unroll
                for (int off = 1; off < 16; off <<= 1) mx = fmaxf(mx, __shfl_xor(mx, off, 64));
                float e0 = exp2f((sc4[0][r] - mx) * 1.44269504f);
                float e1 = exp2f((sc4[1][r] - mx) * 1.44269504f);
                float e2 = exp2f((sc4[2][r] - mx) * 1.44269504f);
                float e3 = exp2f((sc4[3][r] - mx) * 1.44269504f);
                float sum = e0 + e1 + e2 + e3;
                #pragma unroll
                for (int off = 1; off < 16; off <<= 1) sum += __shfl_xor(sum, off, 64);
                float inv = 1.f / sum;
                p[0][r] = e0 * inv; p[1][r] = e1 * inv; p[2][r] = e2 * inv; p[3][r] = e3 * inv;
            }
            #pragma unroll
            for (int n = 0; n < 4; ++n) {   // P^T[g][h]: 4 r-consecutive h -> one b64
                u32x2 pk;
                pk.x = pack2(p[n][0], p[n][1]);
                pk.y = pack2(p[n][2], p[n][3]);
                *(u32x2*)&sE[(n * 16 + l16) * 72 + wid * 16 + g16 * 4] = pk;
            }
        }
        __syncthreads();   // bar2

        // ====== phase C: M-MFMAs FIRST (WC on demand), then v+gate, ONE barrier =======
        {
            // WC fragments for this dir (L2-hot: same 32 KB for all blocks)
            const int rwc = (wid * 16 + l16) * 128 + cb * 64 + g16 * 8;
            bf16x8 wc0 = *(const bf16x8*)&WC[rwc];
            bf16x8 wc1 = *(const bf16x8*)&WC[rwc + 32];
            // M = Wc[:, cb*64 .. +64) @ P  (reads sE P^T, bar2-protected) -> registers
            f32x4 macc[4];
            #pragma unroll
            for (int n = 0; n < 4; ++n) macc[n] = (f32x4){0,0,0,0};
            #pragma unroll
            for (int n = 0; n < 4; ++n) {
                bf16x8 b0 = *(const bf16x8*)&sE[(n * 16 + l16) * 72 + g16 * 8];
                bf16x8 b1 = *(const bf16x8*)&sE[(n * 16 + l16) * 72 + 32 + g16 * 8];
                macc[n] = MFMA(wc0, b0, macc[n]);
                macc[n] = MFMA(wc1, b1, macc[n]);
            }
            // v-proj + gate(q from sC) -> G^T in sD (packed b64)
            #pragma unroll
            for (int m = 0; m < 4; ++m) {
                bf16x8 afr[4];
                #pragma unroll
                for (int k0 = 0; k0 < 4; ++k0)
                    afr[k0] = *(const bf16x8*)&Xv[(m * 16 + l16) * 136 + k0 * 32 + g16 * 8];
                f32x4 va[2];
                va[0] = (f32x4){0,0,0,0}; va[1] = (f32x4){0,0,0,0};
                __builtin_amdgcn_s_setprio(1);
                #pragma unroll
                for (int k0 = 0; k0 < 4; ++k0)
                    #pragma unroll
                    for (int nn = 0; nn < 2; ++nn)
                        va[nn] = MFMA(afr[k0], wvf[nn][k0], va[nn]);
                __builtin_amdgcn_s_setprio(0);
                #pragma unroll
                for (int nn = 0; nn < 2; ++nn) {
                    int sc_ = (wid * 2 + nn) * 16 + l16;
                    float q0 = bf2f(sC[(m * 16 + g16 * 4 + 0) * 136 + sc_]);
                    float q1 = bf2f(sC[(m * 16 + g16 * 4 + 1) * 136 + sc_]);
                    float q2 = bf2f(sC[(m * 16 + g16 * 4 + 2) * 136 + sc_]);
                    float q3 = bf2f(sC[(m * 16 + g16 * 4 + 3) * 136 + sc_]);
                    float g0 = (va[nn][0] + bvv2[nn]) * q0;
                    float g1 = (va[nn][1] + bvv2[nn]) * q1;
                    float g2 = (va[nn][2] + bvv2[nn]) * q2;
                    float g3 = (va[nn][3] + bvv2[nn]) * q3;
                    u32x2 pk;
                    pk.x = pack2(g0, g1);
                    pk.y = pack2(g2, g3);
                    *(u32x2*)&sD[sc_ * 72 + m * 16 + g16 * 4] = pk;   // G^T [s][c]
                }
            }
            __syncthreads();   // bar3: all P^T reads done (M in regs) + all G^T writes done
            // M -> sE (own-wave rows; phase D needs no barrier, only lgkmcnt)
            #pragma unroll
            for (int n = 0; n < 4; ++n)
                #pragma unroll
                for (int r = 0; r < 4; ++r) {
                    int o = wid * 16 + g16 * 4 + r;
                    sE[o * 72 + n * 16 + l16] = f2bf(macc[n][r]);   // M [o][g]
                }
        }

        // ========== phase D: emb += M @ G (M same-wave rows; G^T bar3-protected) ======
        __builtin_amdgcn_s_setprio(1);
        #pragma unroll
        for (int k0 = 0; k0 < 2; ++k0) {
            bf16x8 afr = *(const bf16x8*)&sE[(wid * 16 + l16) * 72 + k0 * 32 + g16 * 8];
            #pragma unroll
            for (int n = 0; n < 8; ++n) {
                bf16x8 bfr = *(const bf16x8*)&sD[(n * 16 + l16) * 72 + k0 * 32 + g16 * 8];
                eacc[n] = MFMA(afr, bfr, eacc[n]);
            }
        }
        __builtin_amdgcn_s_setprio(0);
        if (dir == 0) __syncthreads();   // bar4 only before dir1 reuses sC/sD/sE
    }

    // ---- epilogue: emb + bc -> global ----
    float* eo = out + (size_t)b * 7744;
    {
        float bcv[4];
        #pragma unroll
        for (int r = 0; r < 4; ++r) bcv[r] = bc[wid * 16 + g16 * 4 + r];
        #pragma unroll
        for (int n = 0; n < 8; ++n) {
            int s = n * 16 + l16;
            if (s < SA) {
                #pragma unroll
                for (int r = 0; r < 4; ++r) {
                    int o = wid * 16 + g16 * 4 + r;
                    eo[o * 121 + s] = eacc[n][r] + bcv[r];
                }
            }
        }
    }

    // ---- router MLP (8-way unrolled; sR[0..127] stable since bar0) ----
    if (tid < 128) {
        float a[8];
        #pragma unroll
        for (int j = 0; j < 8; ++j) a[j] = 0.f;
        for (int c = 0; c < 128; c += 8) {
            #pragma unroll
            for (int j = 0; j < 8; ++j)
                a[j] += sR[c + j] * Wr1[(c + j) * 128 + tid];
        }
        float s01 = a[0] + a[1], s23 = a[2] + a[3], s45 = a[4] + a[5], s67 = a[6] + a[7];
        sR[128 + tid] = fmaxf((s01 + s23) + (s45 + s67) + br1[tid], 0.f);
    }
    __syncthreads();
    if (tid < 4) {
        float a[8];
        #pragma unroll
        for (int j = 0; j < 8; ++j) a[j] = 0.f;
        for (int h = 0; h < 128; h += 8) {
            #pragma unroll
            for (int j = 0; j < 8; ++j)
                a[j] += sR[128 + h + j] * Wr2[(h + j) * 4 + tid];
        }
        float s01 = a[0] + a[1], s23 = a[2] + a[3], s45 = a[4] + a[5], s67 = a[6] + a[7];
        sR[256 + tid] = (s01 + s23) + (s45 + s67) + br2[tid];
    }
    __syncthreads();
    if (tid < 4) {
        float m = fmaxf(fmaxf(sR[256], sR[257]), fmaxf(sR[258], sR[259]));
        float e = __expf(sR[256 + tid] - m);
        float s = 0.f;
        for (int p = 0; p < 4; ++p) s += __expf(sR[256 + p] - m);
        out[EMB_TOTAL + b * 4 + tid] = e / s;
    }
}

extern "C" void kernel_launch(void* const* d_in, const int* in_sizes, int n_in,
                              void* d_out, int out_size, void* d_ws, size_t ws_size,
                              hipStream_t stream) {
    const float* lidar = (const float*)d_in[0];
    const float* hsi   = (const float*)d_in[1];
    const float* Wq  = (const float*)d_in[2];  const float* bq  = (const float*)d_in[3];
    const float* Wk  = (const float*)d_in[4];  const float* bk  = (const float*)d_in[5];
    const float* Wv  = (const float*)d_in[6];  const float* bv  = (const float*)d_in[7];
    const float* Wr1 = (const float*)d_in[8];  const float* br1 = (const float*)d_in[9];
    const float* Wr2 = (const float*)d_in[10]; const float* br2 = (const float*)d_in[11];
    const float* Wc  = (const float*)d_in[12]; const float* bc  = (const float*)d_in[13];
    short* wsb = (short*)d_ws;
    float* out = (float*)d_out;

    hipLaunchKernelGGL(convert_weights, dim3(224), dim3(256), 0, stream, Wq, Wk, Wv, Wc, wsb);
    hipLaunchKernelGGL(fused_kernel, dim3(NB), dim3(256), 0, stream,
                       lidar, hsi, bq, bk, bv, Wr1, br1, Wr2, br2, bc, wsb, out);
}